// Round 1
// baseline (214.714 us; speedup 1.0000x reference)
//
#include <hip/hip_runtime.h>
#include <math.h>

constexpr int NCAPS = 1152;
constexpr int CIN   = 8;
constexpr int COUT  = 16;
constexpr int BATCH = 128;
constexpr int DCAPS = 10;
constexpr int RPT   = 3;            // u-rows per thread
constexpr int NTHREADS = 384;       // 384*3 = 1152
constexpr int NWAVES = NTHREADS / 64;

// One block per (d,b). Entire u[d,b,:,:] tile lives in registers (3x16 per
// thread). Routing loop runs fully on-chip; LDS only for reductions.
__global__ __launch_bounds__(NTHREADS, 2) void digitcaps_kernel(
    const float* __restrict__ x,    // [128, 1152, 8]
    const float* __restrict__ w,    // [10, 1152, 8, 16]
    float* __restrict__ out)        // [10, 128, 16]
{
    __shared__ float red[NWAVES][COUT];
    __shared__ float sbuf[NWAVES];
    __shared__ float vsh[COUT];

    // swizzle: consecutive groups of 8 blocks (one per XCD) share d, so each
    // XCD's L2 streams the same 576 KB w[d] slice for 16 consecutive b's.
    const int i = blockIdx.x;
    const int g = i >> 3;
    const int d = g % DCAPS;
    const int b = (g / DCAPS) * 8 + (i & 7);

    const int t    = threadIdx.x;
    const int wave = t >> 6;
    const int lane = t & 63;
    const int n0   = t * RPT;

    // ---- u[r][o] = x[b,n,:] . w[d,n,:,o] ----
    float u[RPT][COUT];
    {
        const float* xb = x + ((size_t)b * NCAPS + n0) * CIN;
        const float* wd = w + ((size_t)d * NCAPS + n0) * (size_t)(CIN * COUT);
        #pragma unroll
        for (int r = 0; r < RPT; ++r) {
            float4 xa = ((const float4*)(xb + r * CIN))[0];
            float4 xc = ((const float4*)(xb + r * CIN))[1];
            float xi[CIN] = {xa.x, xa.y, xa.z, xa.w, xc.x, xc.y, xc.z, xc.w};
            const float4* wr = (const float4*)(wd + (size_t)r * CIN * COUT);
            #pragma unroll
            for (int o = 0; o < COUT; ++o) u[r][o] = 0.f;
            #pragma unroll
            for (int ii = 0; ii < CIN; ++ii) {
                float xv = xi[ii];
                #pragma unroll
                for (int q = 0; q < 4; ++q) {
                    float4 wv = wr[ii * 4 + q];
                    u[r][q*4+0] = fmaf(xv, wv.x, u[r][q*4+0]);
                    u[r][q*4+1] = fmaf(xv, wv.y, u[r][q*4+1]);
                    u[r][q*4+2] = fmaf(xv, wv.z, u[r][q*4+2]);
                    u[r][q*4+3] = fmaf(xv, wv.w, u[r][q*4+3]);
                }
            }
        }
    }

    float bb[RPT] = {0.f, 0.f, 0.f};   // routing logits (same across o)

    #pragma unroll
    for (int it = 0; it < 3; ++it) {
        float cr[RPT];
        float scale;
        if (it == 0) {
            cr[0] = cr[1] = cr[2] = 1.f;        // softmax(0) = uniform
            scale = 1.f / (float)NCAPS;
        } else {
            // block-wide softmax over the 1152 logits
            float m = fmaxf(bb[0], fmaxf(bb[1], bb[2]));
            #pragma unroll
            for (int off = 32; off > 0; off >>= 1)
                m = fmaxf(m, __shfl_down(m, off));
            if (lane == 0) sbuf[wave] = m;
            __syncthreads();
            float M = sbuf[0];
            #pragma unroll
            for (int wv = 1; wv < NWAVES; ++wv) M = fmaxf(M, sbuf[wv]);
            __syncthreads();
            float z = 0.f;
            #pragma unroll
            for (int r = 0; r < RPT; ++r) {
                cr[r] = __expf(bb[r] - M);
                z += cr[r];
            }
            #pragma unroll
            for (int off = 32; off > 0; off >>= 1)
                z += __shfl_down(z, off);
            if (lane == 0) sbuf[wave] = z;
            __syncthreads();
            float Z = 0.f;
            #pragma unroll
            for (int wv = 0; wv < NWAVES; ++wv) Z += sbuf[wv];
            scale = 1.f / Z;
            __syncthreads();   // sbuf reused next iteration
        }

        // s[o] = scale * sum_n c[n] * u[n][o]
        float p[COUT];
        #pragma unroll
        for (int o = 0; o < COUT; ++o)
            p[o] = cr[0]*u[0][o] + cr[1]*u[1][o] + cr[2]*u[2][o];
        #pragma unroll
        for (int off = 32; off > 0; off >>= 1) {
            #pragma unroll
            for (int o = 0; o < COUT; ++o)
                p[o] += __shfl_down(p[o], off);
        }
        if (lane == 0) {
            #pragma unroll
            for (int o = 0; o < COUT; ++o) red[wave][o] = p[o];
        }
        __syncthreads();
        if (t < COUT) {
            float s = 0.f;
            #pragma unroll
            for (int wv = 0; wv < NWAVES; ++wv) s += red[wv][t];
            s *= scale;
            float sq = s * s;
            // coeff*s = s^2/((1+s^2)*|s|) * s = s*|s|/(1+s^2)
            float vv = s * fabsf(s) / (1.f + sq);
            vsh[t] = vv;
            if (it == 2)
                out[((size_t)d * BATCH + b) * COUT + t] = vv;
        }
        __syncthreads();
        if (it < 2) {
            // b[n] += dot(u[n,:], v)
            #pragma unroll
            for (int r = 0; r < RPT; ++r) {
                float dotv = 0.f;
                #pragma unroll
                for (int o = 0; o < COUT; ++o)
                    dotv = fmaf(u[r][o], vsh[o], dotv);
                bb[r] += dotv;
            }
        }
    }
}

extern "C" void kernel_launch(void* const* d_in, const int* in_sizes, int n_in,
                              void* d_out, int out_size, void* d_ws, size_t ws_size,
                              hipStream_t stream) {
    const float* x = (const float*)d_in[0];
    const float* w = (const float*)d_in[1];
    float* out = (float*)d_out;
    digitcaps_kernel<<<DCAPS * BATCH, NTHREADS, 0, stream>>>(x, w, out);
}

// Round 2
// 105.560 us; speedup vs baseline: 2.0340x; 2.0340x over previous
//
#include <hip/hip_runtime.h>
#include <math.h>

constexpr int NCAPS = 1152;
constexpr int CIN   = 8;
constexpr int COUT  = 16;
constexpr int BATCH = 128;
constexpr int DCAPS = 10;
constexpr int NTHREADS = 384;
constexpr int NWAVES = NTHREADS / 64;
constexpr int QPT = 12;   // o-quads per thread: 1152 rows * 4 quads / 384 thr

// One block per (d,b). Lane layout: within a wave, lane = nsub*4 + oq, so a
// w-load instruction reads 16 segments of 64 contiguous bytes (4 lanes x
// float4) at stride 512 -> 16 cache lines/instr instead of 64 (R1 failure).
// Each lane owns u[n][4oq..4oq+3] for 12 rows; routing runs in registers with
// xor-shuffle reductions.
__global__ __launch_bounds__(NTHREADS, 4) void digitcaps_kernel(
    const float* __restrict__ x,    // [128, 1152, 8]
    const float* __restrict__ w,    // [10, 1152, 8, 16]
    float* __restrict__ out)        // [10, 128, 16]
{
    __shared__ float4 red[NWAVES][4];   // per-wave partial s, by oq
    __shared__ float  sbuf[NWAVES];     // softmax max/sum partials
    __shared__ float4 vsh[4];           // squashed v, by oq

    // XCD swizzle: assume block i -> XCD (i&7). Each XCD gets a 5d x 32b
    // rectangle: L2 footprint 5*576KB(w) + 32*36KB(x) ~= 4 MB.
    const int i   = blockIdx.x;
    const int xcd = i & 7;
    const int k   = i >> 3;                    // 0..159
    const int d   = (xcd >> 2) * 5 + (k % 5);  // 0..9
    const int b   = (k / 5) * 4 + (xcd & 3);   // 0..127

    const int t    = threadIdx.x;
    const int wave = t >> 6;
    const int lane = t & 63;
    const int nsub = lane >> 2;   // 0..15: row within 16-row group
    const int oq   = lane & 3;    // 0..3:  o-quad

    const float* xb = x + (size_t)b * NCAPS * CIN;
    const float* wd = w + (size_t)d * NCAPS * CIN * COUT;

    // ---- u4[j] = x[b,n,:] . w[d,n,:,4oq..4oq+3],  n = j*96 + wave*16 + nsub
    float4 u4[QPT];
    #pragma unroll
    for (int j = 0; j < QPT; ++j) {
        const int n = j * 96 + wave * 16 + nsub;
        const float* xr = xb + (size_t)n * CIN;
        const float* wr = wd + (size_t)n * CIN * COUT + oq * 4;
        float4 xa = ((const float4*)xr)[0];
        float4 xc = ((const float4*)xr)[1];
        float xi[CIN] = {xa.x, xa.y, xa.z, xa.w, xc.x, xc.y, xc.z, xc.w};
        float4 acc = {0.f, 0.f, 0.f, 0.f};
        #pragma unroll
        for (int ii = 0; ii < CIN; ++ii) {
            float4 wv = *(const float4*)(wr + ii * COUT);
            acc.x = fmaf(xi[ii], wv.x, acc.x);
            acc.y = fmaf(xi[ii], wv.y, acc.y);
            acc.z = fmaf(xi[ii], wv.z, acc.z);
            acc.w = fmaf(xi[ii], wv.w, acc.w);
        }
        u4[j] = acc;
    }

    float bb[QPT];
    #pragma unroll
    for (int j = 0; j < QPT; ++j) bb[j] = 0.f;

    #pragma unroll
    for (int it = 0; it < 3; ++it) {
        float cc[QPT];
        float scale;
        if (it == 0) {
            #pragma unroll
            for (int j = 0; j < QPT; ++j) cc[j] = 1.f;
            scale = 1.f / (float)NCAPS;
        } else {
            // softmax over the 1152 logits (each n replicated on 4 lanes)
            float m = bb[0];
            #pragma unroll
            for (int j = 1; j < QPT; ++j) m = fmaxf(m, bb[j]);
            #pragma unroll
            for (int off = 1; off < 64; off <<= 1)
                m = fmaxf(m, __shfl_xor(m, off));
            if (lane == 0) sbuf[wave] = m;
            __syncthreads();
            float M = sbuf[0];
            #pragma unroll
            for (int wv = 1; wv < NWAVES; ++wv) M = fmaxf(M, sbuf[wv]);
            __syncthreads();
            float z = 0.f;
            #pragma unroll
            for (int j = 0; j < QPT; ++j) {
                cc[j] = __expf(bb[j] - M);
                z += cc[j];
            }
            #pragma unroll
            for (int off = 1; off < 64; off <<= 1)
                z += __shfl_xor(z, off);
            if (lane == 0) sbuf[wave] = z;
            __syncthreads();
            float Z = 0.f;
            #pragma unroll
            for (int wv = 0; wv < NWAVES; ++wv) Z += sbuf[wv];
            scale = 4.f / Z;   // each n counted 4x (one per oq lane)
            __syncthreads();
        }

        // s partial for this lane's oq block
        float4 p = {0.f, 0.f, 0.f, 0.f};
        #pragma unroll
        for (int j = 0; j < QPT; ++j) {
            p.x = fmaf(cc[j], u4[j].x, p.x);
            p.y = fmaf(cc[j], u4[j].y, p.y);
            p.z = fmaf(cc[j], u4[j].z, p.z);
            p.w = fmaf(cc[j], u4[j].w, p.w);
        }
        // reduce across the 16 row-groups (lanes differing in bits 2..5)
        #pragma unroll
        for (int off = 4; off < 64; off <<= 1) {
            p.x += __shfl_xor(p.x, off);
            p.y += __shfl_xor(p.y, off);
            p.z += __shfl_xor(p.z, off);
            p.w += __shfl_xor(p.w, off);
        }
        if (nsub == 0) red[wave][oq] = p;
        __syncthreads();

        if (t < 4) {   // t == oq: combine waves, squash, publish v
            float4 s = red[0][t];
            #pragma unroll
            for (int wv = 1; wv < NWAVES; ++wv) {
                float4 r = red[wv][t];
                s.x += r.x; s.y += r.y; s.z += r.z; s.w += r.w;
            }
            s.x *= scale; s.y *= scale; s.z *= scale; s.w *= scale;
            float4 v;
            v.x = s.x * fabsf(s.x) / (1.f + s.x * s.x);
            v.y = s.y * fabsf(s.y) / (1.f + s.y * s.y);
            v.z = s.z * fabsf(s.z) / (1.f + s.z * s.z);
            v.w = s.w * fabsf(s.w) / (1.f + s.w * s.w);
            vsh[t] = v;
            if (it == 2)
                ((float4*)(out + ((size_t)d * BATCH + b) * COUT))[t] = v;
        }
        __syncthreads();

        if (it < 2) {
            float4 v = vsh[oq];
            #pragma unroll
            for (int j = 0; j < QPT; ++j) {
                float dotv = u4[j].x * v.x + u4[j].y * v.y +
                             u4[j].z * v.z + u4[j].w * v.w;
                // sum the 4 oq-lanes of this row (bits 0..1)
                dotv += __shfl_xor(dotv, 1);
                dotv += __shfl_xor(dotv, 2);
                bb[j] += dotv;
            }
        }
        __syncthreads();   // vsh/red reused next iteration
    }
}

extern "C" void kernel_launch(void* const* d_in, const int* in_sizes, int n_in,
                              void* d_out, int out_size, void* d_ws, size_t ws_size,
                              hipStream_t stream) {
    const float* x = (const float*)d_in[0];
    const float* w = (const float*)d_in[1];
    float* out = (float*)d_out;
    digitcaps_kernel<<<DCAPS * BATCH, NTHREADS, 0, stream>>>(x, w, out);
}